// Round 6
// baseline (1920.953 us; speedup 1.0000x reference)
//
#include <hip/hip_runtime.h>

// LSTM: B=256, T=8192, I=5, H=16, fc -> 1.
// R6: 32 blocks x 8 waves (512 thr) -> 2 waves per SIMD so two sequences
// interleave and fill each other's dependency bubbles (single-wave R3 was
// 240 issue + 120 bubble cycles/step). Per-step body = R3's proven readlane
// h-dot + permlane gate gather + batched fc projection; x stride-8 packed in
// LDS (b128+b32), 2-slot alternating, double-buffered per 64-step chunk.
// R4 lesson: update_dpp ties old->dst (adds movs). R5 lesson: same-step LDS
// h-broadcast puts LDS latency on the chain.

__device__ __forceinline__ float readlane_f(float v, int l) {
    return __int_as_float(__builtin_amdgcn_readlane(__float_as_int(v), l));
}

__device__ __forceinline__ void plswap32(float& a, float& b) {
#if __has_builtin(__builtin_amdgcn_permlane32_swap)
    auto r = __builtin_amdgcn_permlane32_swap(__float_as_uint(a),
                                              __float_as_uint(b), false, false);
    a = __uint_as_float(r[0]);
    b = __uint_as_float(r[1]);
#else
    unsigned ao, bo;
    asm("v_mov_b32 %0, %2\n\t"
        "v_mov_b32 %1, %3\n\t"
        "v_permlane32_swap_b32 %0, %1"
        : "=&v"(ao), "=&v"(bo)
        : "v"(__float_as_uint(a)), "v"(__float_as_uint(b)));
    a = __uint_as_float(ao);
    b = __uint_as_float(bo);
#endif
}

__device__ __forceinline__ void plswap16(float& a, float& b) {
#if __has_builtin(__builtin_amdgcn_permlane16_swap)
    auto r = __builtin_amdgcn_permlane16_swap(__float_as_uint(a),
                                              __float_as_uint(b), false, false);
    a = __uint_as_float(r[0]);
    b = __uint_as_float(r[1]);
#else
    unsigned ao, bo;
    asm("v_mov_b32 %0, %2\n\t"
        "v_mov_b32 %1, %3\n\t"
        "v_permlane16_swap_b32 %0, %1"
        : "=&v"(ao), "=&v"(bo)
        : "v"(__float_as_uint(a)), "v"(__float_as_uint(b)));
    a = __uint_as_float(ao);
    b = __uint_as_float(bo);
#endif
}

__global__ __launch_bounds__(512, 1) void lstm_fused(
    const float* __restrict__ x,      // [B, T, 5]
    const float* __restrict__ W_ih,   // [64, 5]
    const float* __restrict__ W_hh,   // [64, 16]
    const float* __restrict__ b_ih,   // [64]
    const float* __restrict__ b_hh,   // [64]
    const float* __restrict__ fc_w,   // [1, 16]
    const float* __restrict__ fc_b,   // [1]
    float* __restrict__ out,          // [B, T]
    int T)
{
    const int wid  = threadIdx.x >> 6;          // wave id 0..7
    const int lane = threadIdx.x & 63;          // lane within wave
    const int b    = (blockIdx.x << 3) + wid;   // batch element
    const int jj   = lane & 15;
    const int q    = lane >> 4;
    const bool isg = (q == 2);

    // Pre-scale weights by -log2e (sigmoid) / -2log2e (tanh gate):
    // activation = 1/(1+exp2(pre)) with pre already scaled.
    const float LOG2E  = 1.4426950408889634f;
    const float wscale = isg ? (-2.0f * LOG2E) : (-LOG2E);
    const float post_m = isg ?  2.0f : 1.0f;
    const float post_a = isg ? -1.0f : 0.0f;

    float wi[5];
#pragma unroll
    for (int i = 0; i < 5; ++i) wi[i] = W_ih[lane * 5 + i] * wscale;
    float wh[16];
#pragma unroll
    for (int k = 0; k < 16; ++k) wh[k] = W_hh[lane * 16 + k] * wscale;
    const float bias = (b_ih[lane] + b_hh[lane]) * wscale;

    float fw[16];                      // uniform -> SGPRs
#pragma unroll
    for (int k = 0; k < 16; ++k) fw[k] = fc_w[k];
    const float fcb = fc_b[0];

    // Per-wave LDS regions (waves are fully independent; no barriers).
    __shared__ __align__(16) float ls_xp[8 * 1024];  // 2 halves x 64 rows x 8
    __shared__ float ls_h[8 * 1088];                 // 64 steps x stride 17
    float* __restrict__ xpw = &ls_xp[wid << 10];
    float* __restrict__ hw  = &ls_h[wid * 1088];

    const float* __restrict__ xb = x   + (size_t)b * T * 5;
    float*       __restrict__ yb = out + (size_t)b * T;
    const int NC = T >> 6;             // 64-step chunks

    // ---- Prologue: repack chunk 0 into half 0; chunk 1 rows in rp. ----
    float rp[5];
    {
        const float* g0 = xb + lane * 5;
#pragma unroll
        for (int k = 0; k < 5; ++k) xpw[lane * 8 + k] = g0[k];
        if (NC > 1) {
            const float* g1 = xb + 320 + lane * 5;
#pragma unroll
            for (int k = 0; k < 5; ++k) rp[k] = g1[k];
        } else {
#pragma unroll
            for (int k = 0; k < 5; ++k) rp[k] = 0.0f;
        }
    }

    // Slots: rows 0,1 of chunk 0 (uniform-address broadcast reads).
    float4 sv0 = *(const float4*)&xpw[0];
    float  s40 = xpw[4];
    float4 sv1 = *(const float4*)&xpw[8];
    float  s41 = xpw[12];

    float c = 0.0f, h = 0.0f;

#define LSTM_STEP(SV, S4, TP)                                                 \
    {                                                                         \
        const int tpv = (TP);                                                 \
        /* x-partial seeds (consume slot BEFORE reload) */                    \
        float a0 = fmaf(SV.x, wi[0], bias);                                   \
        float a1 = SV.y * wi[1];                                              \
        float a2 = SV.z * wi[2];                                              \
        float a3 = SV.w * wi[3];                                              \
        a0 = fmaf(S4, wi[4], a0);                                             \
        /* prefetch x row tpv+2 into the slot (distance 2) */                 \
        int w_ = base + (tpv + 2) * 8;                                        \
        w_ = (w_ >= 1024) ? (w_ - 1024) : w_;                                 \
        SV = *(const float4*)&xpw[w_];                                        \
        S4 = xpw[w_ + 4];                                                     \
        /* h-dot: 16 readlane-broadcast FMAs, 4 parallel chains */            \
        a0 = fmaf(readlane_f(h, 0),  wh[0],  a0);                             \
        a0 = fmaf(readlane_f(h, 1),  wh[1],  a0);                             \
        a0 = fmaf(readlane_f(h, 2),  wh[2],  a0);                             \
        a0 = fmaf(readlane_f(h, 3),  wh[3],  a0);                             \
        a1 = fmaf(readlane_f(h, 4),  wh[4],  a1);                             \
        a1 = fmaf(readlane_f(h, 5),  wh[5],  a1);                             \
        a1 = fmaf(readlane_f(h, 6),  wh[6],  a1);                             \
        a1 = fmaf(readlane_f(h, 7),  wh[7],  a1);                             \
        a2 = fmaf(readlane_f(h, 8),  wh[8],  a2);                             \
        a2 = fmaf(readlane_f(h, 9),  wh[9],  a2);                             \
        a2 = fmaf(readlane_f(h, 10), wh[10], a2);                             \
        a2 = fmaf(readlane_f(h, 11), wh[11], a2);                             \
        a3 = fmaf(readlane_f(h, 12), wh[12], a3);                             \
        a3 = fmaf(readlane_f(h, 13), wh[13], a3);                             \
        a3 = fmaf(readlane_f(h, 14), wh[14], a3);                             \
        a3 = fmaf(readlane_f(h, 15), wh[15], a3);                             \
        const float pre = (a0 + a1) + (a2 + a3);                              \
        /* activation: sigma or tanh (=2*sigma(2z)-1) via exp2+rcp */         \
        const float e_  = __builtin_amdgcn_exp2f(pre);                        \
        const float s_  = __builtin_amdgcn_rcpf(1.0f + e_);                   \
        const float act = fmaf(post_m, s_, post_a);                           \
        /* gather i,f,g,o to all lanes */                                     \
        float A1 = act, B1 = act;                                             \
        plswap32(A1, B1);      /* A1=[i,f,i,f], B1=[g,o,g,o] */               \
        float iv = A1, fv = A1;                                               \
        plswap16(iv, fv);                                                     \
        float gv = B1, ov = B1;                                               \
        plswap16(gv, ov);                                                     \
        /* state update */                                                    \
        c = fmaf(fv, c, iv * gv);                                             \
        const float e2 = __builtin_amdgcn_exp2f(c * -2.8853900817779268f);    \
        const float r2 = __builtin_amdgcn_rcpf(1.0f + e2);                    \
        h = ov * fmaf(2.0f, r2, -1.0f);                                       \
        /* stage h for the batched output projection */                       \
        hw[tpv * 17 + jj] = h;                                                \
    }

    for (int n = 0; n < NC; ++n) {
        const int base = (n & 1) * 512;

        // Stage chunk n+1 into the other half; issue loads for chunk n+2.
        if (n + 1 < NC) {
            const int dh = ((n + 1) & 1) * 512;
#pragma unroll
            for (int k = 0; k < 5; ++k) xpw[dh + lane * 8 + k] = rp[k];
            if (n + 2 < NC) {
                const float* g2 = xb + (size_t)(n + 2) * 320 + lane * 5;
#pragma unroll
                for (int k = 0; k < 5; ++k) rp[k] = g2[k];
            }
        }

        for (int tp = 0; tp < 64; tp += 2) {
            LSTM_STEP(sv0, s40, tp);
            LSTM_STEP(sv1, s41, tp + 1);
        }

        // Batched output projection: lane l handles step n*64+l.
        float y = fcb;
#pragma unroll
        for (int k = 0; k < 16; ++k) y = fmaf(hw[lane * 17 + k], fw[k], y);
        yb[(n << 6) + lane] = y;
    }
#undef LSTM_STEP
}

extern "C" void kernel_launch(void* const* d_in, const int* in_sizes, int n_in,
                              void* d_out, int out_size, void* d_ws, size_t ws_size,
                              hipStream_t stream) {
    const float* x    = (const float*)d_in[0];
    const float* W_ih = (const float*)d_in[1];
    const float* W_hh = (const float*)d_in[2];
    const float* b_ih = (const float*)d_in[3];
    const float* b_hh = (const float*)d_in[4];
    const float* fc_w = (const float*)d_in[5];
    const float* fc_b = (const float*)d_in[6];
    float* out = (float*)d_out;

    const int B = 256;
    const int T = out_size / B;   // 8192

    lstm_fused<<<dim3(B / 8), dim3(512), 0, stream>>>(
        x, W_ih, W_hh, b_ih, b_hh, fc_w, fc_b, out, T);
}

// Round 7
// 1919.239 us; speedup vs baseline: 1.0009x; 1.0009x over previous
//
#include <hip/hip_runtime.h>

// LSTM: B=256, T=8192, I=5, H=16, fc -> 1.
// R7: TWO sequences per wave, software-interleaved, 128 blocks x 64 thr
// (1 wave/CU). Sequence B's instructions fill sequence A's chain bubbles
// inside one in-order wave. Per-seq body = R3's proven readlane h-dot +
// permlane gate gather; x stride-8 packed in LDS (b128+b32), 2-slot
// alternation, double-buffered 64-step chunks; batched fc projection.
// R4 lesson: update_dpp ties old->dst (adds movs). R5 lesson: same-step LDS
// h-broadcast puts LDS latency on the chain. R6 lesson: 2 waves/SIMD sums
// exec (480/steppair) - worse than 1 wave + bubbles (359).

__device__ __forceinline__ float readlane_f(float v, int l) {
    return __int_as_float(__builtin_amdgcn_readlane(__float_as_int(v), l));
}

__device__ __forceinline__ void plswap32(float& a, float& b) {
#if __has_builtin(__builtin_amdgcn_permlane32_swap)
    auto r = __builtin_amdgcn_permlane32_swap(__float_as_uint(a),
                                              __float_as_uint(b), false, false);
    a = __uint_as_float(r[0]);
    b = __uint_as_float(r[1]);
#else
    unsigned ao, bo;
    asm("v_mov_b32 %0, %2\n\t"
        "v_mov_b32 %1, %3\n\t"
        "v_permlane32_swap_b32 %0, %1"
        : "=&v"(ao), "=&v"(bo)
        : "v"(__float_as_uint(a)), "v"(__float_as_uint(b)));
    a = __uint_as_float(ao);
    b = __uint_as_float(bo);
#endif
}

__device__ __forceinline__ void plswap16(float& a, float& b) {
#if __has_builtin(__builtin_amdgcn_permlane16_swap)
    auto r = __builtin_amdgcn_permlane16_swap(__float_as_uint(a),
                                              __float_as_uint(b), false, false);
    a = __uint_as_float(r[0]);
    b = __uint_as_float(r[1]);
#else
    unsigned ao, bo;
    asm("v_mov_b32 %0, %2\n\t"
        "v_mov_b32 %1, %3\n\t"
        "v_permlane16_swap_b32 %0, %1"
        : "=&v"(ao), "=&v"(bo)
        : "v"(__float_as_uint(a)), "v"(__float_as_uint(b)));
    a = __uint_as_float(ao);
    b = __uint_as_float(bo);
#endif
}

__global__ __launch_bounds__(64, 1) void lstm_fused(
    const float* __restrict__ x,      // [B, T, 5]
    const float* __restrict__ W_ih,   // [64, 5]
    const float* __restrict__ W_hh,   // [64, 16]
    const float* __restrict__ b_ih,   // [64]
    const float* __restrict__ b_hh,   // [64]
    const float* __restrict__ fc_w,   // [1, 16]
    const float* __restrict__ fc_b,   // [1]
    float* __restrict__ out,          // [B, T]
    int T)
{
    const int lane = threadIdx.x;     // 0..63
    const int jj   = lane & 15;
    const int q    = lane >> 4;
    const bool isg = (q == 2);

    // Shared (per-gate) weights, pre-scaled by -log2e / -2log2e so the
    // activation is 1/(1+exp2(pre)).
    const float LOG2E  = 1.4426950408889634f;
    const float wscale = isg ? (-2.0f * LOG2E) : (-LOG2E);
    const float post_m = isg ?  2.0f : 1.0f;
    const float post_a = isg ? -1.0f : 0.0f;

    float wi[5];
#pragma unroll
    for (int i = 0; i < 5; ++i) wi[i] = W_ih[lane * 5 + i] * wscale;
    float wh[16];
#pragma unroll
    for (int k = 0; k < 16; ++k) wh[k] = W_hh[lane * 16 + k] * wscale;
    const float bias = (b_ih[lane] + b_hh[lane]) * wscale;

    float fw[16];
#pragma unroll
    for (int k = 0; k < 16; ++k) fw[k] = fc_w[k];
    const float fcb = fc_b[0];

    // Two sequences per wave.
    const int b0 = blockIdx.x * 2;
    const int b1 = b0 + 1;

    __shared__ __align__(16) float xpA[1024];   // 2 halves x 64 rows x 8
    __shared__ __align__(16) float xpB[1024];
    __shared__ float hsA[1088];                 // 64 steps x stride 17
    __shared__ float hsB[1088];

    const float* __restrict__ xbA = x + (size_t)b0 * T * 5;
    const float* __restrict__ xbB = x + (size_t)b1 * T * 5;
    float* __restrict__ ybA = out + (size_t)b0 * T;
    float* __restrict__ ybB = out + (size_t)b1 * T;
    const int NC = T >> 6;

    // ---- Prologue: chunk 0 -> LDS half 0 for both seqs; chunk 1 in rp. ----
    float rpA[5], rpB[5];
    {
        const float* gA = xbA + lane * 5;
        const float* gB = xbB + lane * 5;
#pragma unroll
        for (int k = 0; k < 5; ++k) xpA[lane * 8 + k] = gA[k];
#pragma unroll
        for (int k = 0; k < 5; ++k) xpB[lane * 8 + k] = gB[k];
        if (NC > 1) {
            const float* gA1 = xbA + 320 + lane * 5;
            const float* gB1 = xbB + 320 + lane * 5;
#pragma unroll
            for (int k = 0; k < 5; ++k) { rpA[k] = gA1[k]; rpB[k] = gB1[k]; }
        } else {
#pragma unroll
            for (int k = 0; k < 5; ++k) { rpA[k] = 0.0f; rpB[k] = 0.0f; }
        }
    }

    float4 svA0 = *(const float4*)&xpA[0];
    float  s4A0 = xpA[4];
    float4 svA1 = *(const float4*)&xpA[8];
    float  s4A1 = xpA[12];
    float4 svB0 = *(const float4*)&xpB[0];
    float  s4B0 = xpB[4];
    float4 svB1 = *(const float4*)&xpB[8];
    float  s4B1 = xpB[12];

    float cA = 0.0f, hA = 0.0f, cB = 0.0f, hB = 0.0f;

#define STEP2(SVA, S4A, SVB, S4B, TP)                                         \
    {                                                                         \
        const int tpv = (TP);                                                 \
        const int w_  = (base + (tpv + 2) * 8) & 1023;                        \
        /* x-partial seeds, both seqs (consume slots BEFORE reload) */        \
        float aA0 = fmaf(SVA.x, wi[0], bias);                                 \
        float aB0 = fmaf(SVB.x, wi[0], bias);                                 \
        float aA1 = SVA.y * wi[1];                                            \
        float aB1 = SVB.y * wi[1];                                            \
        float aA2 = SVA.z * wi[2];                                            \
        float aB2 = SVB.z * wi[2];                                            \
        float aA3 = SVA.w * wi[3];                                            \
        float aB3 = SVB.w * wi[3];                                            \
        aA0 = fmaf(S4A, wi[4], aA0);                                          \
        aB0 = fmaf(S4B, wi[4], aB0);                                          \
        /* prefetch x row tpv+2 into the slots (distance 2) */                \
        SVA = *(const float4*)&xpA[w_];  S4A = xpA[w_ + 4];                   \
        SVB = *(const float4*)&xpB[w_];  S4B = xpB[w_ + 4];                   \
        /* h-dots: 16 readlane FMAs each, interleaved A/B */                  \
        aA0 = fmaf(readlane_f(hA, 0),  wh[0],  aA0);                          \
        aB0 = fmaf(readlane_f(hB, 0),  wh[0],  aB0);                          \
        aA0 = fmaf(readlane_f(hA, 1),  wh[1],  aA0);                          \
        aB0 = fmaf(readlane_f(hB, 1),  wh[1],  aB0);                          \
        aA0 = fmaf(readlane_f(hA, 2),  wh[2],  aA0);                          \
        aB0 = fmaf(readlane_f(hB, 2),  wh[2],  aB0);                          \
        aA0 = fmaf(readlane_f(hA, 3),  wh[3],  aA0);                          \
        aB0 = fmaf(readlane_f(hB, 3),  wh[3],  aB0);                          \
        aA1 = fmaf(readlane_f(hA, 4),  wh[4],  aA1);                          \
        aB1 = fmaf(readlane_f(hB, 4),  wh[4],  aB1);                          \
        aA1 = fmaf(readlane_f(hA, 5),  wh[5],  aA1);                          \
        aB1 = fmaf(readlane_f(hB, 5),  wh[5],  aB1);                          \
        aA1 = fmaf(readlane_f(hA, 6),  wh[6],  aA1);                          \
        aB1 = fmaf(readlane_f(hB, 6),  wh[6],  aB1);                          \
        aA1 = fmaf(readlane_f(hA, 7),  wh[7],  aA1);                          \
        aB1 = fmaf(readlane_f(hB, 7),  wh[7],  aB1);                          \
        aA2 = fmaf(readlane_f(hA, 8),  wh[8],  aA2);                          \
        aB2 = fmaf(readlane_f(hB, 8),  wh[8],  aB2);                          \
        aA2 = fmaf(readlane_f(hA, 9),  wh[9],  aA2);                          \
        aB2 = fmaf(readlane_f(hB, 9),  wh[9],  aB2);                          \
        aA2 = fmaf(readlane_f(hA, 10), wh[10], aA2);                          \
        aB2 = fmaf(readlane_f(hB, 10), wh[10], aB2);                          \
        aA2 = fmaf(readlane_f(hA, 11), wh[11], aA2);                          \
        aB2 = fmaf(readlane_f(hB, 11), wh[11], aB2);                          \
        aA3 = fmaf(readlane_f(hA, 12), wh[12], aA3);                          \
        aB3 = fmaf(readlane_f(hB, 12), wh[12], aB3);                          \
        aA3 = fmaf(readlane_f(hA, 13), wh[13], aA3);                          \
        aB3 = fmaf(readlane_f(hB, 13), wh[13], aB3);                          \
        aA3 = fmaf(readlane_f(hA, 14), wh[14], aA3);                          \
        aB3 = fmaf(readlane_f(hB, 14), wh[14], aB3);                          \
        aA3 = fmaf(readlane_f(hA, 15), wh[15], aA3);                          \
        aB3 = fmaf(readlane_f(hB, 15), wh[15], aB3);                          \
        const float preA = (aA0 + aA1) + (aA2 + aA3);                         \
        const float preB = (aB0 + aB1) + (aB2 + aB3);                         \
        /* activations */                                                     \
        const float eA  = __builtin_amdgcn_exp2f(preA);                       \
        const float eB  = __builtin_amdgcn_exp2f(preB);                       \
        const float sA  = __builtin_amdgcn_rcpf(1.0f + eA);                   \
        const float sB  = __builtin_amdgcn_rcpf(1.0f + eB);                   \
        const float actA = fmaf(post_m, sA, post_a);                          \
        const float actB = fmaf(post_m, sB, post_a);                          \
        /* gate gathers */                                                    \
        float A1A = actA, B1A = actA;                                         \
        float A1B = actB, B1B = actB;                                         \
        plswap32(A1A, B1A);                                                   \
        plswap32(A1B, B1B);                                                   \
        float ivA = A1A, fvA = A1A;                                           \
        float ivB = A1B, fvB = A1B;                                           \
        plswap16(ivA, fvA);                                                   \
        plswap16(ivB, fvB);                                                   \
        float gvA = B1A, ovA = B1A;                                           \
        float gvB = B1B, ovB = B1B;                                           \
        plswap16(gvA, ovA);                                                   \
        plswap16(gvB, ovB);                                                   \
        /* state updates */                                                   \
        cA = fmaf(fvA, cA, ivA * gvA);                                        \
        cB = fmaf(fvB, cB, ivB * gvB);                                        \
        const float e2A = __builtin_amdgcn_exp2f(cA * -2.8853900817779268f);  \
        const float e2B = __builtin_amdgcn_exp2f(cB * -2.8853900817779268f);  \
        const float r2A = __builtin_amdgcn_rcpf(1.0f + e2A);                  \
        const float r2B = __builtin_amdgcn_rcpf(1.0f + e2B);                  \
        hA = ovA * fmaf(2.0f, r2A, -1.0f);                                    \
        hB = ovB * fmaf(2.0f, r2B, -1.0f);                                    \
        hsA[tpv * 17 + jj] = hA;                                              \
        hsB[tpv * 17 + jj] = hB;                                              \
    }

    for (int n = 0; n < NC; ++n) {
        const int base = (n & 1) * 512;

        // Stage chunk n+1 for both seqs; issue loads for chunk n+2.
        if (n + 1 < NC) {
            const int dh = ((n + 1) & 1) * 512;
#pragma unroll
            for (int k = 0; k < 5; ++k) xpA[dh + lane * 8 + k] = rpA[k];
#pragma unroll
            for (int k = 0; k < 5; ++k) xpB[dh + lane * 8 + k] = rpB[k];
            if (n + 2 < NC) {
                const float* gA2 = xbA + (size_t)(n + 2) * 320 + lane * 5;
                const float* gB2 = xbB + (size_t)(n + 2) * 320 + lane * 5;
#pragma unroll
                for (int k = 0; k < 5; ++k) { rpA[k] = gA2[k]; rpB[k] = gB2[k]; }
            }
        }

        for (int tp = 0; tp < 64; tp += 2) {
            STEP2(svA0, s4A0, svB0, s4B0, tp);
            STEP2(svA1, s4A1, svB1, s4B1, tp + 1);
        }

        // Batched output projections: lane l handles step n*64+l.
        float yA = fcb, yB = fcb;
#pragma unroll
        for (int k = 0; k < 16; ++k) yA = fmaf(hsA[lane * 17 + k], fw[k], yA);
#pragma unroll
        for (int k = 0; k < 16; ++k) yB = fmaf(hsB[lane * 17 + k], fw[k], yB);
        ybA[(n << 6) + lane] = yA;
        ybB[(n << 6) + lane] = yB;
    }
#undef STEP2
}

extern "C" void kernel_launch(void* const* d_in, const int* in_sizes, int n_in,
                              void* d_out, int out_size, void* d_ws, size_t ws_size,
                              hipStream_t stream) {
    const float* x    = (const float*)d_in[0];
    const float* W_ih = (const float*)d_in[1];
    const float* W_hh = (const float*)d_in[2];
    const float* b_ih = (const float*)d_in[3];
    const float* b_hh = (const float*)d_in[4];
    const float* fc_w = (const float*)d_in[5];
    const float* fc_b = (const float*)d_in[6];
    float* out = (float*)d_out;

    const int B = 256;
    const int T = out_size / B;   // 8192

    lstm_fused<<<dim3(B / 2), dim3(64), 0, stream>>>(
        x, W_ih, W_hh, b_ih, b_hh, fc_w, fc_b, out, T);
}

// Round 9
// 1047.651 us; speedup vs baseline: 1.8336x; 1.8319x over previous
//
#include <hip/hip_runtime.h>

// LSTM: B=256, T=8192, I=5, H=16, fc -> 1.  One wave per batch element,
// 256 blocks (R3 structure - best so far, 1225us).
// R8b: instruction diet. h-dot and x-proj via packed f16 v_dot2 (f32 acc):
//   - h pairs built with quad_perm[1,0,3,2] DPP + cvt_pkrtz, broadcast as
//     8 readlanes (was 16), dot via 8 fdot2 (was 16 fma).
//   - x rows packed in LDS as 16B (x01,x23 half2, x4 f32): 1 ds_read_b128.
// R8 compile fix: cvt_pkrtz returns __fp16x2 -> bitcast to _Float16x2.
// Lessons: R4 update_dpp old-tie movs; R5 same-step LDS broadcast latency;
// R6/R7 co-residency & 2-seq interleave raise wall (issue is the binder,
// ~280cyc/step SIMD time invariant).

typedef _Float16 half2v __attribute__((ext_vector_type(2)));
typedef __fp16   fp16x2 __attribute__((ext_vector_type(2)));

__device__ __forceinline__ unsigned readlane_u(unsigned v, int l) {
    return (unsigned)__builtin_amdgcn_readlane((int)v, l);
}
__device__ __forceinline__ half2v pk16(float a, float b) {
    union { fp16x2 f; half2v h; } cc;
    cc.f = __builtin_amdgcn_cvt_pkrtz(a, b);
    return cc.h;
}
__device__ __forceinline__ float dot2(half2v a, half2v b, float c) {
#if __has_builtin(__builtin_amdgcn_fdot2)
    return __builtin_amdgcn_fdot2(a, b, c, false);
#else
    return fmaf((float)a[0], (float)b[0], fmaf((float)a[1], (float)b[1], c));
#endif
}
// lane j -> value of lane j^1 (quad_perm [1,0,3,2] = 0xB1), single dpp mov.
__device__ __forceinline__ float quad_swap1(float v) {
    return __int_as_float(__builtin_amdgcn_update_dpp(
        0, __float_as_int(v), 0xB1, 0xF, 0xF, true));
}
__device__ __forceinline__ unsigned h2u(half2v h) {
    union { half2v h; unsigned u; } cc; cc.h = h; return cc.u;
}
__device__ __forceinline__ half2v u2h(unsigned u) {
    union { half2v h; unsigned u; } cc; cc.u = u; return cc.h;
}

__device__ __forceinline__ void plswap32(float& a, float& b) {
#if __has_builtin(__builtin_amdgcn_permlane32_swap)
    auto r = __builtin_amdgcn_permlane32_swap(__float_as_uint(a),
                                              __float_as_uint(b), false, false);
    a = __uint_as_float(r[0]);
    b = __uint_as_float(r[1]);
#else
    unsigned ao, bo;
    asm("v_mov_b32 %0, %2\n\t"
        "v_mov_b32 %1, %3\n\t"
        "v_permlane32_swap_b32 %0, %1"
        : "=&v"(ao), "=&v"(bo)
        : "v"(__float_as_uint(a)), "v"(__float_as_uint(b)));
    a = __uint_as_float(ao);
    b = __uint_as_float(bo);
#endif
}
__device__ __forceinline__ void plswap16(float& a, float& b) {
#if __has_builtin(__builtin_amdgcn_permlane16_swap)
    auto r = __builtin_amdgcn_permlane16_swap(__float_as_uint(a),
                                              __float_as_uint(b), false, false);
    a = __uint_as_float(r[0]);
    b = __uint_as_float(r[1]);
#else
    unsigned ao, bo;
    asm("v_mov_b32 %0, %2\n\t"
        "v_mov_b32 %1, %3\n\t"
        "v_permlane16_swap_b32 %0, %1"
        : "=&v"(ao), "=&v"(bo)
        : "v"(__float_as_uint(a)), "v"(__float_as_uint(b)));
    a = __uint_as_float(ao);
    b = __uint_as_float(bo);
#endif
}

__global__ __launch_bounds__(64, 1) void lstm_fused(
    const float* __restrict__ x,      // [B, T, 5]
    const float* __restrict__ W_ih,   // [64, 5]
    const float* __restrict__ W_hh,   // [64, 16]
    const float* __restrict__ b_ih,   // [64]
    const float* __restrict__ b_hh,   // [64]
    const float* __restrict__ fc_w,   // [1, 16]
    const float* __restrict__ fc_b,   // [1]
    float* __restrict__ out,          // [B, T]
    int T)
{
    const int lane = threadIdx.x;     // 0..63
    const int jj   = lane & 15;
    const int q    = lane >> 4;
    const bool isg = (q == 2);
    const int b    = blockIdx.x;

    const float LOG2E  = 1.4426950408889634f;
    const float wscale = isg ? (-2.0f * LOG2E) : (-LOG2E);
    const float post_m = isg ?  2.0f : 1.0f;
    const float post_a = isg ? -1.0f : 0.0f;

    const float wi0 = W_ih[lane * 5 + 0] * wscale;
    const float wi1 = W_ih[lane * 5 + 1] * wscale;
    const float wi2 = W_ih[lane * 5 + 2] * wscale;
    const float wi3 = W_ih[lane * 5 + 3] * wscale;
    const float wi4 = W_ih[lane * 5 + 4] * wscale;
    const half2v wip01 = pk16(wi0, wi1);
    const half2v wip23 = pk16(wi2, wi3);

    half2v whp[8];
#pragma unroll
    for (int k = 0; k < 8; ++k)
        whp[k] = pk16(W_hh[lane * 16 + 2 * k] * wscale,
                      W_hh[lane * 16 + 2 * k + 1] * wscale);
    const float bias = (b_ih[lane] + b_hh[lane]) * wscale;

    float fw[16];
#pragma unroll
    for (int k = 0; k < 16; ++k) fw[k] = fc_w[k];
    const float fcb = fc_b[0];

    __shared__ __align__(16) unsigned xp[512];  // 2 halves x 64 rows x 16B
    __shared__ float ls_h[64 * 17];

    const float* __restrict__ xb = x   + (size_t)b * T * 5;
    float*       __restrict__ yb = out + (size_t)b * T;
    const int NC = T >> 6;

    // Prologue: pack chunk 0; chunk 1 raw rows in rp.
    float rp[5];
    {
        const float* g0 = xb + lane * 5;
        uint4 v;
        v.x = h2u(pk16(g0[0], g0[1]));
        v.y = h2u(pk16(g0[2], g0[3]));
        v.z = __float_as_uint(g0[4]);
        v.w = 0u;
        *(uint4*)&xp[lane * 4] = v;
        if (NC > 1) {
            const float* g1 = xb + 320 + lane * 5;
#pragma unroll
            for (int k = 0; k < 5; ++k) rp[k] = g1[k];
        } else {
#pragma unroll
            for (int k = 0; k < 5; ++k) rp[k] = 0.0f;
        }
    }

    uint4 sv0 = *(const uint4*)&xp[0];
    uint4 sv1 = *(const uint4*)&xp[4];

    float c = 0.0f, h = 0.0f;
    unsigned hb0, hb1, hb2, hb3, hb4, hb5, hb6, hb7;
    hb0 = hb1 = hb2 = hb3 = hb4 = hb5 = hb6 = hb7 = 0u;  // f16 pair (0,0)

#define LSTM_STEP(SV, TP)                                                     \
    {                                                                         \
        const int tpv = (TP);                                                 \
        float a0 = dot2(u2h(SV.x), wip01, bias);                              \
        float a1 = dot2(u2h(SV.y), wip23, __uint_as_float(SV.z) * wi4);       \
        const int w_ = (base + (tpv + 2) * 4) & 511;                          \
        SV = *(const uint4*)&xp[w_];                                          \
        a0 = dot2(u2h(hb0), whp[0], a0);                                      \
        a0 = dot2(u2h(hb1), whp[1], a0);                                      \
        a1 = dot2(u2h(hb2), whp[2], a1);                                      \
        a1 = dot2(u2h(hb3), whp[3], a1);                                      \
        float a2 = dot2(u2h(hb4), whp[4], 0.0f);                              \
        a2 = dot2(u2h(hb5), whp[5], a2);                                      \
        float a3 = dot2(u2h(hb6), whp[6], 0.0f);                              \
        a3 = dot2(u2h(hb7), whp[7], a3);                                      \
        const float pre = (a0 + a2) + (a1 + a3);                              \
        const float e_  = __builtin_amdgcn_exp2f(pre);                        \
        const float s_  = __builtin_amdgcn_rcpf(1.0f + e_);                   \
        const float act = fmaf(post_m, s_, post_a);                           \
        float A1 = act, B1 = act;                                             \
        plswap32(A1, B1);                                                     \
        float iv = A1, fv = A1;                                               \
        plswap16(iv, fv);                                                     \
        float gv = B1, ov = B1;                                               \
        plswap16(gv, ov);                                                     \
        c = fmaf(fv, c, iv * gv);                                             \
        const float e2 = __builtin_amdgcn_exp2f(c * -2.8853900817779268f);    \
        const float r2 = __builtin_amdgcn_rcpf(1.0f + e2);                    \
        h = ov * fmaf(2.0f, r2, -1.0f);                                       \
        ls_h[tpv * 17 + jj] = h;                                              \
        const float hsw   = quad_swap1(h);                                    \
        const unsigned hu = h2u(pk16(h, hsw));                                \
        hb0 = readlane_u(hu, 0);                                              \
        hb1 = readlane_u(hu, 2);                                              \
        hb2 = readlane_u(hu, 4);                                              \
        hb3 = readlane_u(hu, 6);                                              \
        hb4 = readlane_u(hu, 8);                                              \
        hb5 = readlane_u(hu, 10);                                             \
        hb6 = readlane_u(hu, 12);                                             \
        hb7 = readlane_u(hu, 14);                                             \
    }

    for (int n = 0; n < NC; ++n) {
        const int base = (n & 1) * 256;

        if (n + 1 < NC) {
            const int dh = ((n + 1) & 1) * 256;
            uint4 v;
            v.x = h2u(pk16(rp[0], rp[1]));
            v.y = h2u(pk16(rp[2], rp[3]));
            v.z = __float_as_uint(rp[4]);
            v.w = 0u;
            *(uint4*)&xp[dh + lane * 4] = v;
            if (n + 2 < NC) {
                const float* g2 = xb + (size_t)(n + 2) * 320 + lane * 5;
#pragma unroll
                for (int k = 0; k < 5; ++k) rp[k] = g2[k];
            }
        }

        for (int tp = 0; tp < 64; tp += 2) {
            LSTM_STEP(sv0, tp);
            LSTM_STEP(sv1, tp + 1);
        }

        float y = fcb;
#pragma unroll
        for (int k = 0; k < 16; ++k) y = fmaf(ls_h[lane * 17 + k], fw[k], y);
        yb[(n << 6) + lane] = y;
    }
#undef LSTM_STEP
}

extern "C" void kernel_launch(void* const* d_in, const int* in_sizes, int n_in,
                              void* d_out, int out_size, void* d_ws, size_t ws_size,
                              hipStream_t stream) {
    const float* x    = (const float*)d_in[0];
    const float* W_ih = (const float*)d_in[1];
    const float* W_hh = (const float*)d_in[2];
    const float* b_ih = (const float*)d_in[3];
    const float* b_hh = (const float*)d_in[4];
    const float* fc_w = (const float*)d_in[5];
    const float* fc_b = (const float*)d_in[6];
    float* out = (float*)d_out;

    const int B = 256;
    const int T = out_size / B;   // 8192

    lstm_fused<<<dim3(B), dim3(64), 0, stream>>>(
        x, W_ih, W_hh, b_ih, b_hh, fc_w, fc_b, out, T);
}

// Round 10
// 1026.937 us; speedup vs baseline: 1.8706x; 1.0202x over previous
//
#include <hip/hip_runtime.h>

// LSTM: B=256, T=8192, I=5, H=16, fc -> 1.  One wave per batch element,
// 256 blocks (best structure; R9 = 1048us, 307 cyc/step).
// R10: h-broadcast via 8x ds_bpermute (uniform indices, LDS permute pipe)
// instead of 8x v_readlane (~8cy each on the serialized SGPR port).
// In-order-lgkmcnt analysis: bp issued end of step t, consumed start of t+1;
// x slot-read for t+2 issued a full step earlier -> already drained (this is
// what killed R5's ds_read variant: 120cy latency in a 40cy window).
// Micros: cell state kept pre-scaled (C = -2log2e*c -> exp2(C) direct);
// h = fma(2ov, r2, -ov); inner loop unrolled x4.
// Lessons: R4 update_dpp old-tie movs; R5 LDS-read broadcast latency;
// R6/R7 co-residency/2-seq interleave raise wall; R9 f16 dot2 diet works.

typedef _Float16 half2v __attribute__((ext_vector_type(2)));
typedef __fp16   fp16x2 __attribute__((ext_vector_type(2)));

__device__ __forceinline__ half2v pk16(float a, float b) {
    union { fp16x2 f; half2v h; } cc;
    cc.f = __builtin_amdgcn_cvt_pkrtz(a, b);
    return cc.h;
}
__device__ __forceinline__ float dot2(half2v a, half2v b, float c) {
#if __has_builtin(__builtin_amdgcn_fdot2)
    return __builtin_amdgcn_fdot2(a, b, c, false);
#else
    return fmaf((float)a[0], (float)b[0], fmaf((float)a[1], (float)b[1], c));
#endif
}
// lane j -> value of lane j^1 (quad_perm [1,0,3,2] = 0xB1), single dpp mov.
__device__ __forceinline__ float quad_swap1(float v) {
    return __int_as_float(__builtin_amdgcn_update_dpp(
        0, __float_as_int(v), 0xB1, 0xF, 0xF, true));
}
__device__ __forceinline__ unsigned h2u(half2v h) {
    union { half2v h; unsigned u; } cc; cc.h = h; return cc.u;
}
__device__ __forceinline__ half2v u2h(unsigned u) {
    union { half2v h; unsigned u; } cc; cc.u = u; return cc.h;
}

__device__ __forceinline__ void plswap32(float& a, float& b) {
#if __has_builtin(__builtin_amdgcn_permlane32_swap)
    auto r = __builtin_amdgcn_permlane32_swap(__float_as_uint(a),
                                              __float_as_uint(b), false, false);
    a = __uint_as_float(r[0]);
    b = __uint_as_float(r[1]);
#else
    unsigned ao, bo;
    asm("v_mov_b32 %0, %2\n\t"
        "v_mov_b32 %1, %3\n\t"
        "v_permlane32_swap_b32 %0, %1"
        : "=&v"(ao), "=&v"(bo)
        : "v"(__float_as_uint(a)), "v"(__float_as_uint(b)));
    a = __uint_as_float(ao);
    b = __uint_as_float(bo);
#endif
}
__device__ __forceinline__ void plswap16(float& a, float& b) {
#if __has_builtin(__builtin_amdgcn_permlane16_swap)
    auto r = __builtin_amdgcn_permlane16_swap(__float_as_uint(a),
                                              __float_as_uint(b), false, false);
    a = __uint_as_float(r[0]);
    b = __uint_as_float(r[1]);
#else
    unsigned ao, bo;
    asm("v_mov_b32 %0, %2\n\t"
        "v_mov_b32 %1, %3\n\t"
        "v_permlane16_swap_b32 %0, %1"
        : "=&v"(ao), "=&v"(bo)
        : "v"(__float_as_uint(a)), "v"(__float_as_uint(b)));
    a = __uint_as_float(ao);
    b = __uint_as_float(bo);
#endif
}

__global__ __launch_bounds__(64, 1) void lstm_fused(
    const float* __restrict__ x,      // [B, T, 5]
    const float* __restrict__ W_ih,   // [64, 5]
    const float* __restrict__ W_hh,   // [64, 16]
    const float* __restrict__ b_ih,   // [64]
    const float* __restrict__ b_hh,   // [64]
    const float* __restrict__ fc_w,   // [1, 16]
    const float* __restrict__ fc_b,   // [1]
    float* __restrict__ out,          // [B, T]
    int T)
{
    const int lane = threadIdx.x;     // 0..63
    const int jj   = lane & 15;
    const int q    = lane >> 4;
    const bool isg = (q == 2);
    const int b    = blockIdx.x;

    const float LOG2E  = 1.4426950408889634f;
    const float KN2    = -2.0f * LOG2E;            // tanh(c) scale
    const float wscale = isg ? (-2.0f * LOG2E) : (-LOG2E);
    const float post_m = isg ?  2.0f : 1.0f;
    const float post_a = isg ? -1.0f : 0.0f;

    const float wi0 = W_ih[lane * 5 + 0] * wscale;
    const float wi1 = W_ih[lane * 5 + 1] * wscale;
    const float wi2 = W_ih[lane * 5 + 2] * wscale;
    const float wi3 = W_ih[lane * 5 + 3] * wscale;
    const float wi4 = W_ih[lane * 5 + 4] * wscale;
    const half2v wip01 = pk16(wi0, wi1);
    const half2v wip23 = pk16(wi2, wi3);

    half2v whp[8];
#pragma unroll
    for (int k = 0; k < 8; ++k)
        whp[k] = pk16(W_hh[lane * 16 + 2 * k] * wscale,
                      W_hh[lane * 16 + 2 * k + 1] * wscale);
    const float bias = (b_ih[lane] + b_hh[lane]) * wscale;

    float fw[16];
#pragma unroll
    for (int k = 0; k < 16; ++k) fw[k] = fc_w[k];
    const float fcb = fc_b[0];

    __shared__ __align__(16) unsigned xp[512];  // 2 halves x 64 rows x 16B
    __shared__ float ls_h[64 * 17];

    const float* __restrict__ xb = x   + (size_t)b * T * 5;
    float*       __restrict__ yb = out + (size_t)b * T;
    const int NC = T >> 6;

    // Prologue: pack chunk 0; chunk 1 raw rows in rp.
    float rp[5];
    {
        const float* g0 = xb + lane * 5;
        uint4 v;
        v.x = h2u(pk16(g0[0], g0[1]));
        v.y = h2u(pk16(g0[2], g0[3]));
        v.z = __float_as_uint(g0[4]);
        v.w = 0u;
        *(uint4*)&xp[lane * 4] = v;
        if (NC > 1) {
            const float* g1 = xb + 320 + lane * 5;
#pragma unroll
            for (int k = 0; k < 5; ++k) rp[k] = g1[k];
        } else {
#pragma unroll
            for (int k = 0; k < 5; ++k) rp[k] = 0.0f;
        }
    }

    uint4 sv0 = *(const uint4*)&xp[0];
    uint4 sv1 = *(const uint4*)&xp[4];

    float C = 0.0f, h = 0.0f;              // C = -2log2e * c (pre-scaled)
    unsigned hb0, hb1, hb2, hb3, hb4, hb5, hb6, hb7;
    hb0 = hb1 = hb2 = hb3 = hb4 = hb5 = hb6 = hb7 = 0u;  // f16 pair (0,0)

#define LSTM_STEP(SV, TP)                                                     \
    {                                                                         \
        const int tpv = (TP);                                                 \
        float a0 = dot2(u2h(SV.x), wip01, bias);                              \
        float a1 = dot2(u2h(SV.y), wip23, __uint_as_float(SV.z) * wi4);       \
        const int w_ = (base + (tpv + 2) * 4) & 511;                          \
        SV = *(const uint4*)&xp[w_];                                          \
        a0 = dot2(u2h(hb0), whp[0], a0);                                      \
        a0 = dot2(u2h(hb1), whp[1], a0);                                      \
        a1 = dot2(u2h(hb2), whp[2], a1);                                      \
        a1 = dot2(u2h(hb3), whp[3], a1);                                      \
        float a2 = dot2(u2h(hb4), whp[4], 0.0f);                              \
        a2 = dot2(u2h(hb5), whp[5], a2);                                      \
        float a3 = dot2(u2h(hb6), whp[6], 0.0f);                              \
        a3 = dot2(u2h(hb7), whp[7], a3);                                      \
        const float pre = (a0 + a2) + (a1 + a3);                              \
        const float e_  = __builtin_amdgcn_exp2f(pre);                        \
        const float s_  = __builtin_amdgcn_rcpf(1.0f + e_);                   \
        const float act = fmaf(post_m, s_, post_a);                           \
        float A1 = act, B1 = act;                                             \
        plswap32(A1, B1);                                                     \
        float iv = A1, fv = A1;                                               \
        plswap16(iv, fv);                                                     \
        float gv = B1, ov = B1;                                               \
        plswap16(gv, ov);                                                     \
        const float ivg = iv * gv;                                            \
        C = fmaf(fv, C, ivg * KN2);                                           \
        const float e2 = __builtin_amdgcn_exp2f(C);                           \
        const float r2 = __builtin_amdgcn_rcpf(1.0f + e2);                    \
        const float ov2 = ov + ov;                                            \
        h = fmaf(ov2, r2, -ov);                                               \
        ls_h[tpv * 17 + jj] = h;                                              \
        const float hsw   = quad_swap1(h);                                    \
        const unsigned hu = h2u(pk16(h, hsw));                                \
        const int hui = (int)hu;                                              \
        hb0 = (unsigned)__builtin_amdgcn_ds_bpermute(bix0, hui);              \
        hb1 = (unsigned)__builtin_amdgcn_ds_bpermute(bix1, hui);              \
        hb2 = (unsigned)__builtin_amdgcn_ds_bpermute(bix2, hui);              \
        hb3 = (unsigned)__builtin_amdgcn_ds_bpermute(bix3, hui);              \
        hb4 = (unsigned)__builtin_amdgcn_ds_bpermute(bix4, hui);              \
        hb5 = (unsigned)__builtin_amdgcn_ds_bpermute(bix5, hui);              \
        hb6 = (unsigned)__builtin_amdgcn_ds_bpermute(bix6, hui);              \
        hb7 = (unsigned)__builtin_amdgcn_ds_bpermute(bix7, hui);              \
    }

    // Loop-invariant uniform bpermute indices (bytes): pair k from lane 2k.
    const int bix0 = 0,  bix1 = 8,  bix2 = 16, bix3 = 24;
    const int bix4 = 32, bix5 = 40, bix6 = 48, bix7 = 56;

    for (int n = 0; n < NC; ++n) {
        const int base = (n & 1) * 256;

        if (n + 1 < NC) {
            const int dh = ((n + 1) & 1) * 256;
            uint4 v;
            v.x = h2u(pk16(rp[0], rp[1]));
            v.y = h2u(pk16(rp[2], rp[3]));
            v.z = __float_as_uint(rp[4]);
            v.w = 0u;
            *(uint4*)&xp[dh + lane * 4] = v;
            if (n + 2 < NC) {
                const float* g2 = xb + (size_t)(n + 2) * 320 + lane * 5;
#pragma unroll
                for (int k = 0; k < 5; ++k) rp[k] = g2[k];
            }
        }

        for (int tp = 0; tp < 64; tp += 4) {
            LSTM_STEP(sv0, tp);
            LSTM_STEP(sv1, tp + 1);
            LSTM_STEP(sv0, tp + 2);
            LSTM_STEP(sv1, tp + 3);
        }

        float y = fcb;
#pragma unroll
        for (int k = 0; k < 16; ++k) y = fmaf(ls_h[lane * 17 + k], fw[k], y);
        yb[(n << 6) + lane] = y;
    }
#undef LSTM_STEP
}

extern "C" void kernel_launch(void* const* d_in, const int* in_sizes, int n_in,
                              void* d_out, int out_size, void* d_ws, size_t ws_size,
                              hipStream_t stream) {
    const float* x    = (const float*)d_in[0];
    const float* W_ih = (const float*)d_in[1];
    const float* W_hh = (const float*)d_in[2];
    const float* b_ih = (const float*)d_in[3];
    const float* b_hh = (const float*)d_in[4];
    const float* fc_w = (const float*)d_in[5];
    const float* fc_b = (const float*)d_in[6];
    float* out = (float*)d_out;

    const int B = 256;
    const int T = out_size / B;   // 8192

    lstm_fused<<<dim3(B), dim3(64), 0, stream>>>(
        x, W_ih, W_hh, b_ih, b_hh, fc_w, fc_b, out, T);
}